// Round 19
// baseline (143.614 us; speedup 1.0000x reference)
//
#include <hip/hip_runtime.h>
#include <hip/hip_bf16.h>

typedef __bf16 bf16_t;
typedef __bf16 bf16x8 __attribute__((ext_vector_type(8)));
typedef float f32x4 __attribute__((ext_vector_type(4)));
typedef float f32x2 __attribute__((ext_vector_type(2)));

#define F 128
#define KEXP 8
#define BM 256          // gemm rows per block (16 waves: 8 row x 2 col)
#define BSTG 32768      // elems per expert B stage (64KB)

#define NB 196          // coarse buckets: col>>8 (256 nodes each)
#define CAP 12288       // per-bucket region capacity
#define CH 4096         // edges per binA block (391 binning blocks)

// ---- pass A: coarse-bin edges into per-bucket regions; extra blocks do Wt.
__global__ __launch_bounds__(256) void k_binA(const int* __restrict__ row,
    const int* __restrict__ col, int* __restrict__ cursor,
    int* __restrict__ region, const float* __restrict__ W,
    bf16_t* __restrict__ Wt, int E, int nbin){
  if ((int)blockIdx.x >= nbin){
    int i8 = (blockIdx.x - nbin)*256 + threadIdx.x;   // 32768 groups of 8
    if (i8 < 32768){
      int kk   = i8 >> 12;
      int frag = (i8 >> 6) & 63;
      int lane = i8 & 63;
      int ks = frag >> 3, cg = frag & 7;
      int n  = cg*16 + (lane & 15);
      int f0 = ks*32 + (lane >> 4)*8;
      bf16x8 v;
      #pragma unroll
      for (int j=0;j<8;j++)
        v[j] = (bf16_t)W[(size_t)kk*32768 + (size_t)(f0+j)*128 + n];
      *reinterpret_cast<bf16x8*>(&Wt[(size_t)i8*8]) = v;
    }
    return;
  }
  __shared__ int stage[CH];
  __shared__ unsigned char stageb[CH];
  __shared__ int hist4[4][NB];
  __shared__ int lcur4[4][NB];
  int tid = threadIdx.x, wid = tid >> 6;
  int base = blockIdx.x * CH;
  int cnt = min(CH, E - base);
  for (int i = tid; i < 4*NB; i += 256) ((int*)hist4)[i] = 0;
  __syncthreads();
  for (int i = tid; i < cnt; i += 256){
    int r = row[base+i], c = col[base+i];
    stage[i] = (r << 8) | (c & 255);
    stageb[i] = (unsigned char)(c >> 8);
    atomicAdd(&hist4[wid][c >> 8], 1);
  }
  __syncthreads();
  for (int b = tid; b < NB; b += 256){
    int h0 = hist4[0][b], h1 = hist4[1][b], h2 = hist4[2][b], h3 = hist4[3][b];
    int gbase = atomicAdd(&cursor[b], h0+h1+h2+h3) + b*CAP;
    lcur4[0][b] = gbase;
    lcur4[1][b] = gbase + h0;
    lcur4[2][b] = gbase + h0 + h1;
    lcur4[3][b] = gbase + h0 + h1 + h2;
  }
  __syncthreads();
  for (int i = tid; i < cnt; i += 256){
    int b = stageb[i];
    int pos = atomicAdd(&lcur4[wid][b], 1);
    region[pos] = stage[i];
  }
}

// ---- pass B: per bucket, histogram 256 local dsts -> deg/offs (region-local
// CSR), counting-sort into bucket.
__global__ __launch_bounds__(256) void k_binB(const int* __restrict__ region,
    const int* __restrict__ cursor, int* __restrict__ deg,
    int* __restrict__ offs, int* __restrict__ bucket, int Nn){
  __shared__ int hist4[4][256];
  __shared__ int loff[256];
  __shared__ int lcur4[4][256];
  int b = blockIdx.x, t = threadIdx.x, wid = t >> 6;
  int cnt = cursor[b];
  const int* src = region + b*CAP;
  for (int i = t; i < 4*256; i += 256) ((int*)hist4)[i] = 0;
  __syncthreads();
  for (int i = t; i < cnt; i += 256) atomicAdd(&hist4[wid][src[i] & 255], 1);
  __syncthreads();
  int h0 = hist4[0][t], h1 = hist4[1][t], h2 = hist4[2][t], h3 = hist4[3][t];
  int v = h0 + h1 + h2 + h3;
  loff[t] = v;
  __syncthreads();
  for (int off=1; off<256; off<<=1){
    int u = (t>=off) ? loff[t-off] : 0;
    __syncthreads();
    loff[t] += u;
    __syncthreads();
  }
  int excl = loff[t] - v;
  int gb = b*CAP;
  int node = b*256 + t;
  if (node < Nn){ deg[node] = v; offs[node] = gb + excl; }
  lcur4[0][t] = gb + excl;
  lcur4[1][t] = gb + excl + h0;
  lcur4[2][t] = gb + excl + h0 + h1;
  lcur4[3][t] = gb + excl + h0 + h1 + h2;
  __syncthreads();
  for (int i = t; i < cnt; i += 256){
    int p = src[i];
    int pos = atomicAdd(&lcur4[wid][p & 255], 1);
    bucket[pos] = p >> 8;
  }
}

// ---- xs8[n][f] = fp8( rsqrt(deg[n]) * x[n][f] ), row-major 128B rows
__global__ void k_prep_xs(const float* __restrict__ x, const int* __restrict__ deg,
                          unsigned int* __restrict__ xs8, int Nn){
  int i = blockIdx.x*256 + threadIdx.x;   // i = n*16 + q, 8 elems each
  if (i < Nn*16){
    int n = i >> 4;
    int d = deg[n];
    float dr = d>0 ? rsqrtf((float)d) : 0.f;
    const float4 f0 = *reinterpret_cast<const float4*>(&x[(size_t)i*8]);
    const float4 f1 = *reinterpret_cast<const float4*>(&x[(size_t)i*8+4]);
    unsigned int lo, hi2;
    lo  = __builtin_amdgcn_cvt_pk_fp8_f32(dr*f0.x, dr*f0.y, 0,  false);
    lo  = __builtin_amdgcn_cvt_pk_fp8_f32(dr*f0.z, dr*f0.w, lo, true);
    hi2 = __builtin_amdgcn_cvt_pk_fp8_f32(dr*f1.x, dr*f1.y, 0,  false);
    hi2 = __builtin_amdgcn_cvt_pk_fp8_f32(dr*f1.z, dr*f1.w, hi2, true);
    xs8[(size_t)i*2]     = lo;
    xs8[(size_t)i*2 + 1] = hi2;
  }
}

// ---- gather-aggregate, node-per-16-lane-group, fp8 gathers (R13 form)
__global__ __launch_bounds__(256) void k_agg(const unsigned int* __restrict__ xs8,
    const int* __restrict__ offs, const int* __restrict__ deg,
    const int* __restrict__ bucket, bf16_t* __restrict__ hi, int Nn){
  int wid = threadIdx.x >> 6, lane = threadIdx.x & 63;
  int g = lane >> 4, j16 = lane & 15;
  int n = blockIdx.x*16 + wid*4 + g;
  if (n >= Nn) return;
  int o0 = offs[n];
  int dn = deg[n];
  int o1 = o0 + dn;
  float acc[8] = {0.f,0.f,0.f,0.f,0.f,0.f,0.f,0.f};
  int nr = (dn + 7) >> 3;
  int j = o0;
  for (int r = 0; r < nr; r++, j += 8){
    int idx[8];
    #pragma unroll
    for (int t=0;t<8;t++) idx[t] = bucket[min(j+t, o1-1)];
    uint2 v[8];
    #pragma unroll
    for (int t=0;t<8;t++)
      v[t] = *reinterpret_cast<const uint2*>(
          reinterpret_cast<const unsigned char*>(xs8) + (size_t)idx[t]*F + j16*8);
    #pragma unroll
    for (int t=0;t<8;t++){
      float m = (j+t < o1) ? 1.f : 0.f;
      f32x2 p0 = __builtin_amdgcn_cvt_pk_f32_fp8(v[t].x, false);
      f32x2 p1 = __builtin_amdgcn_cvt_pk_f32_fp8(v[t].x, true);
      f32x2 p2 = __builtin_amdgcn_cvt_pk_f32_fp8(v[t].y, false);
      f32x2 p3 = __builtin_amdgcn_cvt_pk_f32_fp8(v[t].y, true);
      acc[0] += m*p0.x; acc[1] += m*p0.y;
      acc[2] += m*p1.x; acc[3] += m*p1.y;
      acc[4] += m*p2.x; acc[5] += m*p2.y;
      acc[6] += m*p3.x; acc[7] += m*p3.y;
    }
  }
  float dc = dn>0 ? rsqrtf((float)dn) : 0.f;
  bf16x8 o;
  #pragma unroll
  for (int i=0;i<8;i++) o[i] = (bf16_t)(dc*acc[i]);
  *reinterpret_cast<bf16x8*>(&hi[(size_t)n*F + j16*8]) = o;
}

#define MFMA_BF16 __builtin_amdgcn_mfma_f32_16x16x32_bf16

// ---- fused gated expert GEMM, 16-wave col-split (R13 cadence, 2x waves):
// 1024 thr = 8 row-waves x 2 col-waves; each wave = R13's proven per-wave
// shape (32 rows, a[2][8]=64 regs, acc[2][4]=32) but only 64 cols -> reads
// half the stage. 4 waves/SIMD doubles latency hiding. DMA 4x16B/thread,
// counted vmcnt(4).
__global__ __launch_bounds__(1024, 4) void k_gemm(
    const bf16_t* __restrict__ hi, const float* __restrict__ x,
    const float* __restrict__ e, const bf16_t* __restrict__ Wt,
    float* __restrict__ out, int Nn)
{
  extern __shared__ __align__(16) char smem[];     // 2*64KB B + 8KB e
  bf16_t* b_s  = (bf16_t*)smem;
  float*  e_sT = (float*)(smem + 2*BSTG*2);        // [kk][256 rows]
  const int tid = threadIdx.x;
  const int base = blockIdx.x * BM;
  const int lane = tid & 63, wid = tid >> 6;       // 16 waves
  const int rw = wid & 7, cw = wid >> 3;           // 8 row x 2 col
  const int r16 = lane & 15, kc = lane >> 4;

  // issue expert-0 B DMA immediately (4 x 16B per thread)
  #pragma unroll
  for (int i=0;i<4;i++){
    int u = tid + i*1024;
    __builtin_amdgcn_global_load_lds(
        (const __attribute__((address_space(1))) void*)(Wt + (size_t)u*8),
        (__attribute__((address_space(3))) void*)(b_s + (size_t)u*8),
        16, 0, 0);
  }

  // stage e gates: e_sT[kk][row]
  for (int i = tid; i < KEXP*BM; i += 1024){
    int kk = i >> 8, row = i & (BM-1);
    int srow = min(base + row, Nn-1);
    e_sT[kk*BM + row] = e[(size_t)srow*KEXP + kk];
  }

  // A frags: rows rw*32 + {0,16} + r16, full K=256 (hi || bf16(x))
  int rA = min(base + rw*32 + r16,      Nn-1);
  int rB = min(base + rw*32 + 16 + r16, Nn-1);
  bf16x8 a[2][8];
  #pragma unroll
  for (int ks=0; ks<4; ks++){
    a[0][ks] = *reinterpret_cast<const bf16x8*>(&hi[(size_t)rA*F + ks*32 + kc*8]);
    a[1][ks] = *reinterpret_cast<const bf16x8*>(&hi[(size_t)rB*F + ks*32 + kc*8]);
  }
  #pragma unroll
  for (int ks=0; ks<4; ks++){
    const float4 f0 = *reinterpret_cast<const float4*>(&x[(size_t)rA*F + ks*32 + kc*8]);
    const float4 f1 = *reinterpret_cast<const float4*>(&x[(size_t)rA*F + ks*32 + kc*8 + 4]);
    bf16x8 v;
    v[0]=(bf16_t)f0.x; v[1]=(bf16_t)f0.y; v[2]=(bf16_t)f0.z; v[3]=(bf16_t)f0.w;
    v[4]=(bf16_t)f1.x; v[5]=(bf16_t)f1.y; v[6]=(bf16_t)f1.z; v[7]=(bf16_t)f1.w;
    a[0][4+ks] = v;
    const float4 g0 = *reinterpret_cast<const float4*>(&x[(size_t)rB*F + ks*32 + kc*8]);
    const float4 g1 = *reinterpret_cast<const float4*>(&x[(size_t)rB*F + ks*32 + kc*8 + 4]);
    bf16x8 u;
    u[0]=(bf16_t)g0.x; u[1]=(bf16_t)g0.y; u[2]=(bf16_t)g0.z; u[3]=(bf16_t)g0.w;
    u[4]=(bf16_t)g1.x; u[5]=(bf16_t)g1.y; u[6]=(bf16_t)g1.z; u[7]=(bf16_t)g1.w;
    a[1][4+ks] = u;
  }

  f32x4 acc[2][4];
  #pragma unroll
  for (int rg=0;rg<2;rg++)
    #pragma unroll
    for (int cg=0;cg<4;cg++) acc[rg][cg] = (f32x4){0.f,0.f,0.f,0.f};
  const f32x4 fz = (f32x4){0.f,0.f,0.f,0.f};

  // prologue sync: my DMA + everyone's e_sT writes done
  asm volatile("s_waitcnt vmcnt(0) lgkmcnt(0)" ::: "memory");
  __builtin_amdgcn_s_barrier();

  for (int kk=0; kk<8; kk++){
    // issue next expert's B DMA into the other buffer
    if (kk < 7){
      const bf16_t* src = Wt + (size_t)(kk+1)*BSTG;
      bf16_t* dst = b_s + ((kk+1)&1)*BSTG;
      #pragma unroll
      for (int i=0;i<4;i++){
        int u = tid + i*1024;
        __builtin_amdgcn_global_load_lds(
            (const __attribute__((address_space(1))) void*)(src + (size_t)u*8),
            (__attribute__((address_space(3))) void*)(dst + (size_t)u*8),
            16, 0, 0);
      }
      asm volatile("s_waitcnt vmcnt(4)" ::: "memory");  // my stage-kk loads done
    } else {
      asm volatile("s_waitcnt vmcnt(0)" ::: "memory");
    }
    __builtin_amdgcn_s_barrier();   // B1: buf[kk&1] globally ready

    const bf16_t* buf = b_s + (kk&1)*BSTG;
    f32x4 ev0 = *reinterpret_cast<const f32x4*>(&e_sT[kk*BM + rw*32 + kc*4]);
    f32x4 ev1 = *reinterpret_cast<const f32x4*>(&e_sT[kk*BM + rw*32 + 16 + kc*4]);

    // this wave's 4 col-groups: frag = ks*8 + cw*4 + cg
    f32x4 ck[2][4];
    #pragma unroll
    for (int cg=0; cg<4; cg++){
      bf16x8 b = *reinterpret_cast<const bf16x8*>(
          &buf[(size_t)(cw*4 + cg)*512 + lane*8]);
      ck[0][cg] = MFMA_BF16(a[0][0], b, fz, 0, 0, 0);
      ck[1][cg] = MFMA_BF16(a[1][0], b, fz, 0, 0, 0);
    }
    #pragma unroll
    for (int ks=1; ks<8; ks++)
      #pragma unroll
      for (int cg=0; cg<4; cg++){
        bf16x8 b = *reinterpret_cast<const bf16x8*>(
            &buf[(size_t)(ks*8 + cw*4 + cg)*512 + lane*8]);
        ck[0][cg] = MFMA_BF16(a[0][ks], b, ck[0][cg], 0, 0, 0);
        ck[1][cg] = MFMA_BF16(a[1][ks], b, ck[1][cg], 0, 0, 0);
      }
    #pragma unroll
    for (int cg=0; cg<4; cg++)
      #pragma unroll
      for (int r=0; r<4; r++){
        acc[0][cg][r] += ev0[r]*ck[0][cg][r];
        acc[1][cg][r] += ev1[r]*ck[1][cg][r];
      }

    __builtin_amdgcn_s_barrier();   // B2: reads done before buf re-staged
  }

  // epilogue: + residual (this wave's 64-col half)
  #pragma unroll
  for (int rg=0; rg<2; rg++){
    #pragma unroll
    for (int cg=0; cg<4; cg++){
      int ocol = cw*64 + cg*16 + r16;
      #pragma unroll
      for (int r=0; r<4; r++){
        int node = base + rw*32 + rg*16 + kc*4 + r;
        if (node < Nn)
          out[(size_t)node*F + ocol] = acc[rg][cg][r] + x[(size_t)node*F + ocol];
      }
    }
  }
}

extern "C" void kernel_launch(void* const* d_in, const int* in_sizes, int n_in,
                              void* d_out, int out_size, void* d_ws, size_t ws_size,
                              hipStream_t stream){
  const float* x  = (const float*)d_in[0];
  const int*  adj = (const int*)d_in[1];
  const float* e  = (const float*)d_in[2];
  const float* W  = (const float*)d_in[3];
  float* out = (float*)d_out;
  int Nn = in_sizes[0] / F;     // 50000
  int E  = in_sizes[1] / 2;     // 1600000
  const int* rowp = adj;
  const int* colp = adj + E;

  char* w = (char*)d_ws;
  auto alloc = [&](size_t b){ char* p = w; w += (b + 255) & ~(size_t)255; return p; };
  int* deg     = (int*)alloc((size_t)Nn*4);
  int* offs    = (int*)alloc((size_t)Nn*4);
  int* cursor  = (int*)alloc((size_t)NB*4);
  int* bucket  = (int*)alloc((size_t)NB*CAP*4);   // region-local CSR (9.63MB)
  char* uni    = alloc((size_t)NB*CAP*4);   // region (9.63MB); xs8 (6.4MB) aliases
  int* region  = (int*)uni;                 // dead after k_binB
  unsigned int* xs8 = (unsigned int*)uni;   // live from k_prep_xs
  bf16_t* hi   = (bf16_t*)alloc((size_t)Nn*F*2);
  bf16_t* Wt   = (bf16_t*)alloc((size_t)2048*F*2);

  const int smem_bytes = 2*BSTG*2 + KEXP*BM*4;   // 131072 + 8192 = 139264
  hipFuncSetAttribute((const void*)k_gemm,
                      hipFuncAttributeMaxDynamicSharedMemorySize, smem_bytes);

  int nbin = (E + CH - 1) / CH;              // 391
  int xsB  = (Nn*16 + 255)/256;              // 3125
  hipMemsetAsync(cursor, 0, (size_t)NB*4, stream);
  k_binA<<<nbin + 128, 256, 0, stream>>>(rowp, colp, cursor, region, W, Wt, E, nbin);
  k_binB<<<NB, 256, 0, stream>>>(region, cursor, deg, offs, bucket, Nn);
  k_prep_xs<<<xsB, 256, 0, stream>>>(x, deg, xs8, Nn);
  k_agg<<<(Nn+15)/16, 256, 0, stream>>>(xs8, offs, deg, bucket, hi, Nn);
  k_gemm<<<(Nn+BM-1)/BM, 1024, smem_bytes, stream>>>(hi, x, e, Wt, out, Nn);
}

// Round 20
// 138.679 us; speedup vs baseline: 1.0356x; 1.0356x over previous
//
#include <hip/hip_runtime.h>
#include <hip/hip_bf16.h>

typedef __bf16 bf16_t;
typedef __bf16 bf16x8 __attribute__((ext_vector_type(8)));
typedef float f32x4 __attribute__((ext_vector_type(4)));
typedef float f32x2 __attribute__((ext_vector_type(2)));

#define F 128
#define KEXP 8
#define BM 256          // gemm rows per block (8 waves x 32 rows)
#define SSTG 16384      // elems per (expert, col-half) stage (32KB)

#define NB 196          // coarse buckets: col>>8 (256 nodes each)
#define CAP 12288       // per-bucket region capacity
#define CH 4096         // edges per binA block (391 binning blocks)

// ---- pass A: coarse-bin edges into per-bucket regions; extra blocks do Wt.
// Wt: 16 stages of 16384 elems; stage st: kk=st>>1 (expert), nh=st&1 (col-half).
// frag = ks*4 + cg (ks 0..7, cg 0..3), 512 elems; lane l, elem j:
//   f = ks*32 + (l>>4)*8 + j, n = nh*64 + cg*16 + (l&15), src = W[kk][f][n].
__global__ __launch_bounds__(256) void k_binA(const int* __restrict__ row,
    const int* __restrict__ col, int* __restrict__ cursor,
    int* __restrict__ region, const float* __restrict__ W,
    bf16_t* __restrict__ Wt, int E, int nbin){
  if ((int)blockIdx.x >= nbin){
    int i8 = (blockIdx.x - nbin)*256 + threadIdx.x;   // 32768 groups of 8
    if (i8 < 32768){
      int st   = i8 >> 11;            // 2048 groups per stage
      int g    = i8 & 2047;
      int frag = g >> 6;              // 0..31
      int lane = g & 63;
      int kk = st >> 1, nh = st & 1;
      int ks = frag >> 2, cg = frag & 3;
      int n  = nh*64 + cg*16 + (lane & 15);
      int f0 = ks*32 + (lane >> 4)*8;
      bf16x8 v;
      #pragma unroll
      for (int j=0;j<8;j++)
        v[j] = (bf16_t)W[(size_t)kk*32768 + (size_t)(f0+j)*128 + n];
      *reinterpret_cast<bf16x8*>(&Wt[(size_t)i8*8]) = v;
    }
    return;
  }
  __shared__ int stage[CH];
  __shared__ unsigned char stageb[CH];
  __shared__ int hist4[4][NB];
  __shared__ int lcur4[4][NB];
  int tid = threadIdx.x, wid = tid >> 6;
  int base = blockIdx.x * CH;
  int cnt = min(CH, E - base);
  for (int i = tid; i < 4*NB; i += 256) ((int*)hist4)[i] = 0;
  __syncthreads();
  for (int i = tid; i < cnt; i += 256){
    int r = row[base+i], c = col[base+i];
    stage[i] = (r << 8) | (c & 255);
    stageb[i] = (unsigned char)(c >> 8);
    atomicAdd(&hist4[wid][c >> 8], 1);
  }
  __syncthreads();
  for (int b = tid; b < NB; b += 256){
    int h0 = hist4[0][b], h1 = hist4[1][b], h2 = hist4[2][b], h3 = hist4[3][b];
    int gbase = atomicAdd(&cursor[b], h0+h1+h2+h3) + b*CAP;
    lcur4[0][b] = gbase;
    lcur4[1][b] = gbase + h0;
    lcur4[2][b] = gbase + h0 + h1;
    lcur4[3][b] = gbase + h0 + h1 + h2;
  }
  __syncthreads();
  for (int i = tid; i < cnt; i += 256){
    int b = stageb[i];
    int pos = atomicAdd(&lcur4[wid][b], 1);
    region[pos] = stage[i];
  }
}

// ---- pass B: per bucket, histogram 256 local dsts -> deg/offs (region-local
// CSR), counting-sort into bucket.
__global__ __launch_bounds__(256) void k_binB(const int* __restrict__ region,
    const int* __restrict__ cursor, int* __restrict__ deg,
    int* __restrict__ offs, int* __restrict__ bucket, int Nn){
  __shared__ int hist4[4][256];
  __shared__ int loff[256];
  __shared__ int lcur4[4][256];
  int b = blockIdx.x, t = threadIdx.x, wid = t >> 6;
  int cnt = cursor[b];
  const int* src = region + b*CAP;
  for (int i = t; i < 4*256; i += 256) ((int*)hist4)[i] = 0;
  __syncthreads();
  for (int i = t; i < cnt; i += 256) atomicAdd(&hist4[wid][src[i] & 255], 1);
  __syncthreads();
  int h0 = hist4[0][t], h1 = hist4[1][t], h2 = hist4[2][t], h3 = hist4[3][t];
  int v = h0 + h1 + h2 + h3;
  loff[t] = v;
  __syncthreads();
  for (int off=1; off<256; off<<=1){
    int u = (t>=off) ? loff[t-off] : 0;
    __syncthreads();
    loff[t] += u;
    __syncthreads();
  }
  int excl = loff[t] - v;
  int gb = b*CAP;
  int node = b*256 + t;
  if (node < Nn){ deg[node] = v; offs[node] = gb + excl; }
  lcur4[0][t] = gb + excl;
  lcur4[1][t] = gb + excl + h0;
  lcur4[2][t] = gb + excl + h0 + h1;
  lcur4[3][t] = gb + excl + h0 + h1 + h2;
  __syncthreads();
  for (int i = t; i < cnt; i += 256){
    int p = src[i];
    int pos = atomicAdd(&lcur4[wid][p & 255], 1);
    bucket[pos] = p >> 8;
  }
}

// ---- xs8[n][f] = fp8( rsqrt(deg[n]) * x[n][f] ), row-major 128B rows
__global__ void k_prep_xs(const float* __restrict__ x, const int* __restrict__ deg,
                          unsigned int* __restrict__ xs8, int Nn){
  int i = blockIdx.x*256 + threadIdx.x;   // i = n*16 + q, 8 elems each
  if (i < Nn*16){
    int n = i >> 4;
    int d = deg[n];
    float dr = d>0 ? rsqrtf((float)d) : 0.f;
    const float4 f0 = *reinterpret_cast<const float4*>(&x[(size_t)i*8]);
    const float4 f1 = *reinterpret_cast<const float4*>(&x[(size_t)i*8+4]);
    unsigned int lo, hi2;
    lo  = __builtin_amdgcn_cvt_pk_fp8_f32(dr*f0.x, dr*f0.y, 0,  false);
    lo  = __builtin_amdgcn_cvt_pk_fp8_f32(dr*f0.z, dr*f0.w, lo, true);
    hi2 = __builtin_amdgcn_cvt_pk_fp8_f32(dr*f1.x, dr*f1.y, 0,  false);
    hi2 = __builtin_amdgcn_cvt_pk_fp8_f32(dr*f1.z, dr*f1.w, hi2, true);
    xs8[(size_t)i*2]     = lo;
    xs8[(size_t)i*2 + 1] = hi2;
  }
}

// ---- gather-aggregate, node-per-16-lane-group, fp8 gathers (R13 form)
__global__ __launch_bounds__(256) void k_agg(const unsigned int* __restrict__ xs8,
    const int* __restrict__ offs, const int* __restrict__ deg,
    const int* __restrict__ bucket, bf16_t* __restrict__ hi, int Nn){
  int wid = threadIdx.x >> 6, lane = threadIdx.x & 63;
  int g = lane >> 4, j16 = lane & 15;
  int n = blockIdx.x*16 + wid*4 + g;
  if (n >= Nn) return;
  int o0 = offs[n];
  int dn = deg[n];
  int o1 = o0 + dn;
  float acc[8] = {0.f,0.f,0.f,0.f,0.f,0.f,0.f,0.f};
  int nr = (dn + 7) >> 3;
  int j = o0;
  for (int r = 0; r < nr; r++, j += 8){
    int idx[8];
    #pragma unroll
    for (int t=0;t<8;t++) idx[t] = bucket[min(j+t, o1-1)];
    uint2 v[8];
    #pragma unroll
    for (int t=0;t<8;t++)
      v[t] = *reinterpret_cast<const uint2*>(
          reinterpret_cast<const unsigned char*>(xs8) + (size_t)idx[t]*F + j16*8);
    #pragma unroll
    for (int t=0;t<8;t++){
      float m = (j+t < o1) ? 1.f : 0.f;
      f32x2 p0 = __builtin_amdgcn_cvt_pk_f32_fp8(v[t].x, false);
      f32x2 p1 = __builtin_amdgcn_cvt_pk_f32_fp8(v[t].x, true);
      f32x2 p2 = __builtin_amdgcn_cvt_pk_f32_fp8(v[t].y, false);
      f32x2 p3 = __builtin_amdgcn_cvt_pk_f32_fp8(v[t].y, true);
      acc[0] += m*p0.x; acc[1] += m*p0.y;
      acc[2] += m*p1.x; acc[3] += m*p1.y;
      acc[4] += m*p2.x; acc[5] += m*p2.y;
      acc[6] += m*p3.x; acc[7] += m*p3.y;
    }
  }
  float dc = dn>0 ? rsqrtf((float)dn) : 0.f;
  bf16x8 o;
  #pragma unroll
  for (int i=0;i<8;i++) o[i] = (bf16_t)(dc*acc[i]);
  *reinterpret_cast<bf16x8*>(&hi[(size_t)n*F + j16*8]) = o;
}

#define MFMA_BF16 __builtin_amdgcn_mfma_f32_16x16x32_bf16

// ---- fused gated expert GEMM, col-half grid (R13 compile config):
// grid = 196 row-blocks x 2 col-halves = 392 blocks; block = 512 thr = 8
// row-waves x (32 rows x 64 cols). Per-wave a[2][8]=64 regs (R13 shape),
// acc[2][4]=32 (half R13). Stage = (expert, col-half) 32KB; dbuf 64KB +
// e 8KB = 72KB -> 2 blocks/CU. DMA 4x16B/thread, counted vmcnt(4),
// R13 barrier cadence.
__global__ __launch_bounds__(512, 2) void k_gemm(
    const bf16_t* __restrict__ hi, const float* __restrict__ x,
    const float* __restrict__ e, const bf16_t* __restrict__ Wt,
    float* __restrict__ out, int Nn)
{
  extern __shared__ __align__(16) char smem[];     // 2*32KB B + 8KB e = 72KB
  bf16_t* b_s  = (bf16_t*)smem;
  float*  e_sT = (float*)(smem + 2*SSTG*2);        // [kk][256 rows]
  const int tid = threadIdx.x;
  const int rblk = blockIdx.x >> 1, nh = blockIdx.x & 1;
  const int base = rblk * BM;
  const int lane = tid & 63, wid = tid >> 6;       // 8 row-waves
  const int r16 = lane & 15, kc = lane >> 4;

  // issue stage (kk=0, nh) DMA immediately (4 x 16B per thread)
  {
    const bf16_t* src = Wt + (size_t)nh*SSTG;
    #pragma unroll
    for (int i=0;i<4;i++){
      int u = tid + i*512;
      __builtin_amdgcn_global_load_lds(
          (const __attribute__((address_space(1))) void*)(src + (size_t)u*8),
          (__attribute__((address_space(3))) void*)(b_s + (size_t)u*8),
          16, 0, 0);
    }
  }

  // stage e gates: e_sT[kk][row]
  for (int i = tid; i < KEXP*BM; i += 512){
    int kk = i >> 8, row = i & (BM-1);
    int srow = min(base + row, Nn-1);
    e_sT[kk*BM + row] = e[(size_t)srow*KEXP + kk];
  }

  // A frags: rows wid*32 + {0,16} + r16, full K=256 (hi || bf16(x))
  int rA = min(base + wid*32 + r16,      Nn-1);
  int rB = min(base + wid*32 + 16 + r16, Nn-1);
  bf16x8 a[2][8];
  #pragma unroll
  for (int ks=0; ks<4; ks++){
    a[0][ks] = *reinterpret_cast<const bf16x8*>(&hi[(size_t)rA*F + ks*32 + kc*8]);
    a[1][ks] = *reinterpret_cast<const bf16x8*>(&hi[(size_t)rB*F + ks*32 + kc*8]);
  }
  #pragma unroll
  for (int ks=0; ks<4; ks++){
    const float4 f0 = *reinterpret_cast<const float4*>(&x[(size_t)rA*F + ks*32 + kc*8]);
    const float4 f1 = *reinterpret_cast<const float4*>(&x[(size_t)rA*F + ks*32 + kc*8 + 4]);
    bf16x8 v;
    v[0]=(bf16_t)f0.x; v[1]=(bf16_t)f0.y; v[2]=(bf16_t)f0.z; v[3]=(bf16_t)f0.w;
    v[4]=(bf16_t)f1.x; v[5]=(bf16_t)f1.y; v[6]=(bf16_t)f1.z; v[7]=(bf16_t)f1.w;
    a[0][4+ks] = v;
    const float4 g0 = *reinterpret_cast<const float4*>(&x[(size_t)rB*F + ks*32 + kc*8]);
    const float4 g1 = *reinterpret_cast<const float4*>(&x[(size_t)rB*F + ks*32 + kc*8 + 4]);
    bf16x8 u;
    u[0]=(bf16_t)g0.x; u[1]=(bf16_t)g0.y; u[2]=(bf16_t)g0.z; u[3]=(bf16_t)g0.w;
    u[4]=(bf16_t)g1.x; u[5]=(bf16_t)g1.y; u[6]=(bf16_t)g1.z; u[7]=(bf16_t)g1.w;
    a[1][4+ks] = u;
  }

  f32x4 acc[2][4];
  #pragma unroll
  for (int rg=0;rg<2;rg++)
    #pragma unroll
    for (int cg=0;cg<4;cg++) acc[rg][cg] = (f32x4){0.f,0.f,0.f,0.f};
  const f32x4 fz = (f32x4){0.f,0.f,0.f,0.f};

  // prologue sync: my DMA + everyone's e_sT writes done
  asm volatile("s_waitcnt vmcnt(0) lgkmcnt(0)" ::: "memory");
  __builtin_amdgcn_s_barrier();

  for (int kk=0; kk<8; kk++){
    // issue next expert's stage (kk+1, nh) into the other buffer
    if (kk < 7){
      const bf16_t* src = Wt + (size_t)((kk+1)*2 + nh)*SSTG;
      bf16_t* dst = b_s + ((kk+1)&1)*SSTG;
      #pragma unroll
      for (int i=0;i<4;i++){
        int u = tid + i*512;
        __builtin_amdgcn_global_load_lds(
            (const __attribute__((address_space(1))) void*)(src + (size_t)u*8),
            (__attribute__((address_space(3))) void*)(dst + (size_t)u*8),
            16, 0, 0);
      }
      asm volatile("s_waitcnt vmcnt(4)" ::: "memory");  // my stage-kk loads done
    } else {
      asm volatile("s_waitcnt vmcnt(0)" ::: "memory");
    }
    __builtin_amdgcn_s_barrier();   // B1: buf[kk&1] globally ready

    const bf16_t* buf = b_s + (kk&1)*SSTG;
    f32x4 ev0 = *reinterpret_cast<const f32x4*>(&e_sT[kk*BM + wid*32 + kc*4]);
    f32x4 ev1 = *reinterpret_cast<const f32x4*>(&e_sT[kk*BM + wid*32 + 16 + kc*4]);

    f32x4 ck[2][4];
    #pragma unroll
    for (int cg=0; cg<4; cg++){
      bf16x8 b = *reinterpret_cast<const bf16x8*>(
          &buf[(size_t)cg*512 + lane*8]);
      ck[0][cg] = MFMA_BF16(a[0][0], b, fz, 0, 0, 0);
      ck[1][cg] = MFMA_BF16(a[1][0], b, fz, 0, 0, 0);
    }
    #pragma unroll
    for (int ks=1; ks<8; ks++)
      #pragma unroll
      for (int cg=0; cg<4; cg++){
        bf16x8 b = *reinterpret_cast<const bf16x8*>(
            &buf[(size_t)(ks*4 + cg)*512 + lane*8]);
        ck[0][cg] = MFMA_BF16(a[0][ks], b, ck[0][cg], 0, 0, 0);
        ck[1][cg] = MFMA_BF16(a[1][ks], b, ck[1][cg], 0, 0, 0);
      }
    #pragma unroll
    for (int cg=0; cg<4; cg++)
      #pragma unroll
      for (int r=0; r<4; r++){
        acc[0][cg][r] += ev0[r]*ck[0][cg][r];
        acc[1][cg][r] += ev1[r]*ck[1][cg][r];
      }

    __builtin_amdgcn_s_barrier();   // B2: reads done before buf re-staged
  }

  // epilogue: + residual (this block's 64-col half)
  #pragma unroll
  for (int rg=0; rg<2; rg++){
    #pragma unroll
    for (int cg=0; cg<4; cg++){
      int ocol = nh*64 + cg*16 + r16;
      #pragma unroll
      for (int r=0; r<4; r++){
        int node = base + wid*32 + rg*16 + kc*4 + r;
        if (node < Nn)
          out[(size_t)node*F + ocol] = acc[rg][cg][r] + x[(size_t)node*F + ocol];
      }
    }
  }
}

extern "C" void kernel_launch(void* const* d_in, const int* in_sizes, int n_in,
                              void* d_out, int out_size, void* d_ws, size_t ws_size,
                              hipStream_t stream){
  const float* x  = (const float*)d_in[0];
  const int*  adj = (const int*)d_in[1];
  const float* e  = (const float*)d_in[2];
  const float* W  = (const float*)d_in[3];
  float* out = (float*)d_out;
  int Nn = in_sizes[0] / F;     // 50000
  int E  = in_sizes[1] / 2;     // 1600000
  const int* rowp = adj;
  const int* colp = adj + E;

  char* w = (char*)d_ws;
  auto alloc = [&](size_t b){ char* p = w; w += (b + 255) & ~(size_t)255; return p; };
  int* deg     = (int*)alloc((size_t)Nn*4);
  int* offs    = (int*)alloc((size_t)Nn*4);
  int* cursor  = (int*)alloc((size_t)NB*4);
  int* bucket  = (int*)alloc((size_t)NB*CAP*4);   // region-local CSR (9.63MB)
  char* uni    = alloc((size_t)NB*CAP*4);   // region (9.63MB); xs8 (6.4MB) aliases
  int* region  = (int*)uni;                 // dead after k_binB
  unsigned int* xs8 = (unsigned int*)uni;   // live from k_prep_xs
  bf16_t* hi   = (bf16_t*)alloc((size_t)Nn*F*2);
  bf16_t* Wt   = (bf16_t*)alloc((size_t)2048*F*2);

  const int smem_bytes = 2*SSTG*2 + KEXP*BM*4;   // 65536 + 8192 = 73728
  hipFuncSetAttribute((const void*)k_gemm,
                      hipFuncAttributeMaxDynamicSharedMemorySize, smem_bytes);

  int nbin = (E + CH - 1) / CH;              // 391
  int xsB  = (Nn*16 + 255)/256;              // 3125
  int gblk = ((Nn + BM - 1)/BM) * 2;         // 392
  hipMemsetAsync(cursor, 0, (size_t)NB*4, stream);
  k_binA<<<nbin + 128, 256, 0, stream>>>(rowp, colp, cursor, region, W, Wt, E, nbin);
  k_binB<<<NB, 256, 0, stream>>>(region, cursor, deg, offs, bucket, Nn);
  k_prep_xs<<<xsB, 256, 0, stream>>>(x, deg, xs8, Nn);
  k_agg<<<(Nn+15)/16, 256, 0, stream>>>(xs8, offs, deg, bucket, hi, Nn);
  k_gemm<<<gblk, 512, smem_bytes, stream>>>(hi, x, e, Wt, out, Nn);
}

// Round 21
// 132.219 us; speedup vs baseline: 1.0862x; 1.0489x over previous
//
#include <hip/hip_runtime.h>
#include <hip/hip_bf16.h>

typedef __bf16 bf16_t;
typedef __bf16 bf16x8 __attribute__((ext_vector_type(8)));
typedef float f32x4 __attribute__((ext_vector_type(4)));
typedef float f32x2 __attribute__((ext_vector_type(2)));

#define F 128
#define KEXP 8
#define BM 256          // gemm rows per block (8 waves x 32 rows)
#define BSTG 32768      // elems per expert B stage (64KB)

#define NB 196          // coarse buckets: col>>8 (256 nodes each)
#define CAP 12288       // per-bucket region capacity
#define CH 4096         // edges per binA block (391 binning blocks)

// ---- pass A: coarse-bin edges into per-bucket regions; extra blocks do Wt.
// Wt expert-major frag-linear: Wt[kk*32768 + (ks*8+cg)*512 + lane*8 + j],
//   f = ks*32 + (lane>>4)*8 + j, n = cg*16 + (lane&15), src = W[kk][f][n].
__global__ __launch_bounds__(256) void k_binA(const int* __restrict__ row,
    const int* __restrict__ col, int* __restrict__ cursor,
    int* __restrict__ region, const float* __restrict__ W,
    bf16_t* __restrict__ Wt, int E, int nbin){
  if ((int)blockIdx.x >= nbin){
    int i8 = (blockIdx.x - nbin)*256 + threadIdx.x;   // 32768 groups of 8
    if (i8 < 32768){
      int kk   = i8 >> 12;
      int frag = (i8 >> 6) & 63;
      int lane = i8 & 63;
      int ks = frag >> 3, cg = frag & 7;
      int n  = cg*16 + (lane & 15);
      int f0 = ks*32 + (lane >> 4)*8;
      bf16x8 v;
      #pragma unroll
      for (int j=0;j<8;j++)
        v[j] = (bf16_t)W[(size_t)kk*32768 + (size_t)(f0+j)*128 + n];
      *reinterpret_cast<bf16x8*>(&Wt[(size_t)i8*8]) = v;
    }
    return;
  }
  __shared__ int stage[CH];
  __shared__ unsigned char stageb[CH];
  __shared__ int hist4[4][NB];
  __shared__ int lcur4[4][NB];
  int tid = threadIdx.x, wid = tid >> 6;
  int base = blockIdx.x * CH;
  int cnt = min(CH, E - base);
  for (int i = tid; i < 4*NB; i += 256) ((int*)hist4)[i] = 0;
  __syncthreads();
  for (int i = tid; i < cnt; i += 256){
    int r = row[base+i], c = col[base+i];
    stage[i] = (r << 8) | (c & 255);
    stageb[i] = (unsigned char)(c >> 8);
    atomicAdd(&hist4[wid][c >> 8], 1);
  }
  __syncthreads();
  for (int b = tid; b < NB; b += 256){
    int h0 = hist4[0][b], h1 = hist4[1][b], h2 = hist4[2][b], h3 = hist4[3][b];
    int gbase = atomicAdd(&cursor[b], h0+h1+h2+h3) + b*CAP;
    lcur4[0][b] = gbase;
    lcur4[1][b] = gbase + h0;
    lcur4[2][b] = gbase + h0 + h1;
    lcur4[3][b] = gbase + h0 + h1 + h2;
  }
  __syncthreads();
  for (int i = tid; i < cnt; i += 256){
    int b = stageb[i];
    int pos = atomicAdd(&lcur4[wid][b], 1);
    region[pos] = stage[i];
  }
}

// ---- pass B: per bucket, histogram 256 local dsts -> deg/offs (region-local
// CSR: offs[n] = b*CAP + excl, length = deg[n]), counting-sort into bucket.
__global__ __launch_bounds__(256) void k_binB(const int* __restrict__ region,
    const int* __restrict__ cursor, int* __restrict__ deg,
    int* __restrict__ offs, int* __restrict__ bucket, int Nn){
  __shared__ int hist4[4][256];
  __shared__ int loff[256];
  __shared__ int lcur4[4][256];
  int b = blockIdx.x, t = threadIdx.x, wid = t >> 6;
  int cnt = cursor[b];
  const int* src = region + b*CAP;
  for (int i = t; i < 4*256; i += 256) ((int*)hist4)[i] = 0;
  __syncthreads();
  for (int i = t; i < cnt; i += 256) atomicAdd(&hist4[wid][src[i] & 255], 1);
  __syncthreads();
  int h0 = hist4[0][t], h1 = hist4[1][t], h2 = hist4[2][t], h3 = hist4[3][t];
  int v = h0 + h1 + h2 + h3;
  loff[t] = v;
  __syncthreads();
  for (int off=1; off<256; off<<=1){
    int u = (t>=off) ? loff[t-off] : 0;
    __syncthreads();
    loff[t] += u;
    __syncthreads();
  }
  int excl = loff[t] - v;
  int gb = b*CAP;
  int node = b*256 + t;
  if (node < Nn){ deg[node] = v; offs[node] = gb + excl; }
  lcur4[0][t] = gb + excl;
  lcur4[1][t] = gb + excl + h0;
  lcur4[2][t] = gb + excl + h0 + h1;
  lcur4[3][t] = gb + excl + h0 + h1 + h2;
  __syncthreads();
  for (int i = t; i < cnt; i += 256){
    int p = src[i];
    int pos = atomicAdd(&lcur4[wid][p & 255], 1);
    bucket[pos] = p >> 8;
  }
}

// ---- xs8[n][f] = fp8( rsqrt(deg[n]) * x[n][f] ), row-major 128B rows
__global__ void k_prep_xs(const float* __restrict__ x, const int* __restrict__ deg,
                          unsigned int* __restrict__ xs8, int Nn){
  int i = blockIdx.x*256 + threadIdx.x;   // i = n*16 + q, 8 elems each
  if (i < Nn*16){
    int n = i >> 4;
    int d = deg[n];
    float dr = d>0 ? rsqrtf((float)d) : 0.f;
    const float4 f0 = *reinterpret_cast<const float4*>(&x[(size_t)i*8]);
    const float4 f1 = *reinterpret_cast<const float4*>(&x[(size_t)i*8+4]);
    unsigned int lo, hi2;
    lo  = __builtin_amdgcn_cvt_pk_fp8_f32(dr*f0.x, dr*f0.y, 0,  false);
    lo  = __builtin_amdgcn_cvt_pk_fp8_f32(dr*f0.z, dr*f0.w, lo, true);
    hi2 = __builtin_amdgcn_cvt_pk_fp8_f32(dr*f1.x, dr*f1.y, 0,  false);
    hi2 = __builtin_amdgcn_cvt_pk_fp8_f32(dr*f1.z, dr*f1.w, hi2, true);
    xs8[(size_t)i*2]     = lo;
    xs8[(size_t)i*2 + 1] = hi2;
  }
}

// ---- gather-aggregate, node-per-16-lane-group, fp8 gathers
__global__ __launch_bounds__(256) void k_agg(const unsigned int* __restrict__ xs8,
    const int* __restrict__ offs, const int* __restrict__ deg,
    const int* __restrict__ bucket, bf16_t* __restrict__ hi, int Nn){
  int wid = threadIdx.x >> 6, lane = threadIdx.x & 63;
  int g = lane >> 4, j16 = lane & 15;
  int n = blockIdx.x*16 + wid*4 + g;
  if (n >= Nn) return;
  int o0 = offs[n];
  int dn = deg[n];
  int o1 = o0 + dn;
  float acc[8] = {0.f,0.f,0.f,0.f,0.f,0.f,0.f,0.f};
  int nr = (dn + 7) >> 3;
  int j = o0;
  for (int r = 0; r < nr; r++, j += 8){
    int idx[8];
    #pragma unroll
    for (int t=0;t<8;t++) idx[t] = bucket[min(j+t, o1-1)];
    uint2 v[8];
    #pragma unroll
    for (int t=0;t<8;t++)
      v[t] = *reinterpret_cast<const uint2*>(
          reinterpret_cast<const unsigned char*>(xs8) + (size_t)idx[t]*F + j16*8);
    #pragma unroll
    for (int t=0;t<8;t++){
      float m = (j+t < o1) ? 1.f : 0.f;
      f32x2 p0 = __builtin_amdgcn_cvt_pk_f32_fp8(v[t].x, false);
      f32x2 p1 = __builtin_amdgcn_cvt_pk_f32_fp8(v[t].x, true);
      f32x2 p2 = __builtin_amdgcn_cvt_pk_f32_fp8(v[t].y, false);
      f32x2 p3 = __builtin_amdgcn_cvt_pk_f32_fp8(v[t].y, true);
      acc[0] += m*p0.x; acc[1] += m*p0.y;
      acc[2] += m*p1.x; acc[3] += m*p1.y;
      acc[4] += m*p2.x; acc[5] += m*p2.y;
      acc[6] += m*p3.x; acc[7] += m*p3.y;
    }
  }
  float dc = dn>0 ? rsqrtf((float)dn) : 0.f;
  bf16x8 o;
  #pragma unroll
  for (int i=0;i<8;i++) o[i] = (bf16_t)(dc*acc[i]);
  *reinterpret_cast<bf16x8*>(&hi[(size_t)n*F + j16*8]) = o;
}

#define MFMA_BF16 __builtin_amdgcn_mfma_f32_16x16x32_bf16

// ---- fused gated expert GEMM, expert-staged LDS DMA (proven form):
// BM=256, 512 thr = 8 waves x 32 rows; A (full K=256) register-resident.
// 8 expert stages of 64KB, 2x dbuf, counted vmcnt(8), raw barriers.
__global__ __launch_bounds__(512, 2) void k_gemm(
    const bf16_t* __restrict__ hi, const float* __restrict__ x,
    const float* __restrict__ e, const bf16_t* __restrict__ Wt,
    float* __restrict__ out, int Nn)
{
  extern __shared__ __align__(16) char smem[];     // 2*64KB B + 8KB e
  bf16_t* b_s  = (bf16_t*)smem;
  float*  e_sT = (float*)(smem + 2*BSTG*2);        // [kk][256 rows]
  const int tid = threadIdx.x;
  const int base = blockIdx.x * BM;
  const int lane = tid & 63, wid = tid >> 6;
  const int r16 = lane & 15, kc = lane >> 4;

  // issue expert-0 B DMA immediately (latency head start)
  #pragma unroll
  for (int i=0;i<8;i++){
    int u = tid + i*512;
    __builtin_amdgcn_global_load_lds(
        (const __attribute__((address_space(1))) void*)(Wt + (size_t)u*8),
        (__attribute__((address_space(3))) void*)(b_s + (size_t)u*8),
        16, 0, 0);
  }

  // stage e gates: e_sT[kk][row]
  for (int i = tid; i < KEXP*BM; i += 512){
    int kk = i >> 8, row = i & (BM-1);
    int srow = min(base + row, Nn-1);
    e_sT[kk*BM + row] = e[(size_t)srow*KEXP + kk];
  }

  // A frags: rows wid*32 + {0,16} + r16, full K=256 (hi || bf16(x))
  int rA = min(base + wid*32 + r16,      Nn-1);
  int rB = min(base + wid*32 + 16 + r16, Nn-1);
  bf16x8 a[2][8];
  #pragma unroll
  for (int ks=0; ks<4; ks++){
    a[0][ks] = *reinterpret_cast<const bf16x8*>(&hi[(size_t)rA*F + ks*32 + kc*8]);
    a[1][ks] = *reinterpret_cast<const bf16x8*>(&hi[(size_t)rB*F + ks*32 + kc*8]);
  }
  #pragma unroll
  for (int ks=0; ks<4; ks++){
    const float4 f0 = *reinterpret_cast<const float4*>(&x[(size_t)rA*F + ks*32 + kc*8]);
    const float4 f1 = *reinterpret_cast<const float4*>(&x[(size_t)rA*F + ks*32 + kc*8 + 4]);
    bf16x8 v;
    v[0]=(bf16_t)f0.x; v[1]=(bf16_t)f0.y; v[2]=(bf16_t)f0.z; v[3]=(bf16_t)f0.w;
    v[4]=(bf16_t)f1.x; v[5]=(bf16_t)f1.y; v[6]=(bf16_t)f1.z; v[7]=(bf16_t)f1.w;
    a[0][4+ks] = v;
    const float4 g0 = *reinterpret_cast<const float4*>(&x[(size_t)rB*F + ks*32 + kc*8]);
    const float4 g1 = *reinterpret_cast<const float4*>(&x[(size_t)rB*F + ks*32 + kc*8 + 4]);
    bf16x8 u;
    u[0]=(bf16_t)g0.x; u[1]=(bf16_t)g0.y; u[2]=(bf16_t)g0.z; u[3]=(bf16_t)g0.w;
    u[4]=(bf16_t)g1.x; u[5]=(bf16_t)g1.y; u[6]=(bf16_t)g1.z; u[7]=(bf16_t)g1.w;
    a[1][4+ks] = u;
  }

  f32x4 acc[2][8];
  #pragma unroll
  for (int rg=0;rg<2;rg++)
    #pragma unroll
    for (int cg=0;cg<8;cg++) acc[rg][cg] = (f32x4){0.f,0.f,0.f,0.f};
  const f32x4 fz = (f32x4){0.f,0.f,0.f,0.f};

  // prologue sync: my DMA + everyone's e_sT writes done
  asm volatile("s_waitcnt vmcnt(0) lgkmcnt(0)" ::: "memory");
  __builtin_amdgcn_s_barrier();

  for (int kk=0; kk<8; kk++){
    // issue next expert's B DMA into the other buffer
    if (kk < 7){
      const bf16_t* src = Wt + (size_t)(kk+1)*BSTG;
      bf16_t* dst = b_s + ((kk+1)&1)*BSTG;
      #pragma unroll
      for (int i=0;i<8;i++){
        int u = tid + i*512;
        __builtin_amdgcn_global_load_lds(
            (const __attribute__((address_space(1))) void*)(src + (size_t)u*8),
            (__attribute__((address_space(3))) void*)(dst + (size_t)u*8),
            16, 0, 0);
      }
      asm volatile("s_waitcnt vmcnt(8)" ::: "memory");  // my stage-kk loads done
    } else {
      asm volatile("s_waitcnt vmcnt(0)" ::: "memory");
    }
    __builtin_amdgcn_s_barrier();   // B1: buf[kk&1] globally ready

    const bf16_t* buf = b_s + (kk&1)*BSTG;
    f32x4 ev0 = *reinterpret_cast<const f32x4*>(&e_sT[kk*BM + wid*32 + kc*4]);
    f32x4 ev1 = *reinterpret_cast<const f32x4*>(&e_sT[kk*BM + wid*32 + 16 + kc*4]);

    #pragma unroll
    for (int cgh=0; cgh<2; cgh++){
      f32x4 ck[2][4];
      #pragma unroll
      for (int cg=0; cg<4; cg++){
        bf16x8 b = *reinterpret_cast<const bf16x8*>(
            &buf[(size_t)(cgh*4 + cg)*512 + lane*8]);
        ck[0][cg] = MFMA_BF16(a[0][0], b, fz, 0, 0, 0);
        ck[1][cg] = MFMA_BF16(a[1][0], b, fz, 0, 0, 0);
      }
      #pragma unroll
      for (int ks=1; ks<8; ks++)
        #pragma unroll
        for (int cg=0; cg<4; cg++){
          bf16x8 b = *reinterpret_cast<const bf16x8*>(
              &buf[(size_t)(ks*8 + cgh*4 + cg)*512 + lane*8]);
          ck[0][cg] = MFMA_BF16(a[0][ks], b, ck[0][cg], 0, 0, 0);
          ck[1][cg] = MFMA_BF16(a[1][ks], b, ck[1][cg], 0, 0, 0);
        }
      #pragma unroll
      for (int cg=0; cg<4; cg++)
        #pragma unroll
        for (int r=0; r<4; r++){
          acc[0][cgh*4+cg][r] += ev0[r]*ck[0][cg][r];
          acc[1][cgh*4+cg][r] += ev1[r]*ck[1][cg][r];
        }
    }

    __builtin_amdgcn_s_barrier();   // B2: reads done before buf re-staged
  }

  // epilogue: + residual
  #pragma unroll
  for (int rg=0; rg<2; rg++){
    #pragma unroll
    for (int cg=0; cg<8; cg++){
      int ocol = cg*16 + r16;
      #pragma unroll
      for (int r=0; r<4; r++){
        int node = base + wid*32 + rg*16 + kc*4 + r;
        if (node < Nn)
          out[(size_t)node*F + ocol] = acc[rg][cg][r] + x[(size_t)node*F + ocol];
      }
    }
  }
}

extern "C" void kernel_launch(void* const* d_in, const int* in_sizes, int n_in,
                              void* d_out, int out_size, void* d_ws, size_t ws_size,
                              hipStream_t stream){
  const float* x  = (const float*)d_in[0];
  const int*  adj = (const int*)d_in[1];
  const float* e  = (const float*)d_in[2];
  const float* W  = (const float*)d_in[3];
  float* out = (float*)d_out;
  int Nn = in_sizes[0] / F;     // 50000
  int E  = in_sizes[1] / 2;     // 1600000
  const int* rowp = adj;
  const int* colp = adj + E;

  char* w = (char*)d_ws;
  auto alloc = [&](size_t b){ char* p = w; w += (b + 255) & ~(size_t)255; return p; };
  int* deg     = (int*)alloc((size_t)Nn*4);
  int* offs    = (int*)alloc((size_t)Nn*4);
  int* cursor  = (int*)alloc((size_t)NB*4);
  int* bucket  = (int*)alloc((size_t)NB*CAP*4);   // region-local CSR (9.63MB)
  char* uni    = alloc((size_t)NB*CAP*4);   // region (9.63MB); xs8 (6.4MB) aliases
  int* region  = (int*)uni;                 // dead after k_binB
  unsigned int* xs8 = (unsigned int*)uni;   // live from k_prep_xs
  bf16_t* hi   = (bf16_t*)alloc((size_t)Nn*F*2);
  bf16_t* Wt   = (bf16_t*)alloc((size_t)2048*F*2);

  const int smem_bytes = 2*BSTG*2 + KEXP*BM*4;   // 131072 + 8192 = 139264
  hipFuncSetAttribute((const void*)k_gemm,
                      hipFuncAttributeMaxDynamicSharedMemorySize, smem_bytes);

  int nbin = (E + CH - 1) / CH;              // 391
  int xsB  = (Nn*16 + 255)/256;              // 3125
  hipMemsetAsync(cursor, 0, (size_t)NB*4, stream);
  k_binA<<<nbin + 128, 256, 0, stream>>>(rowp, colp, cursor, region, W, Wt, E, nbin);
  k_binB<<<NB, 256, 0, stream>>>(region, cursor, deg, offs, bucket, Nn);
  k_prep_xs<<<xsB, 256, 0, stream>>>(x, deg, xs8, Nn);
  k_agg<<<(Nn+15)/16, 256, 0, stream>>>(xs8, offs, deg, bucket, hi, Nn);
  k_gemm<<<(Nn+BM-1)/BM, 512, smem_bytes, stream>>>(hi, x, e, Wt, out, Nn);
}